// Round 4
// baseline (464.949 us; speedup 1.0000x reference)
//
#include <hip/hip_runtime.h>
#include <hip/hip_cooperative_groups.h>

namespace cg = cooperative_groups;

#define NEDGE 625000
#define NNODE 50000
#define WPITCH 136  // lW pitch in shorts: 272 B rows -> 2-way bank aliasing on b128 (free)
#define EPITCH 68   // uv epilogue pitch in shorts
#define NTILE ((NEDGE + 127) / 128)  // 4883 edge tiles
#define NUNIT ((NNODE + 15) / 16)    // 3125 uv units (16 rows each)

typedef __bf16 bf16x8 __attribute__((ext_vector_type(8)));
typedef unsigned short u16x8 __attribute__((ext_vector_type(8)));
typedef float f32x4 __attribute__((ext_vector_type(4)));

// Native casts: __bf16 cast is RNE in HW; compiler pairs them (v_cvt_pk_bf16_f32).
__device__ __forceinline__ unsigned short f32_bf16(float f) {
  __bf16 h = (__bf16)f;
  return __builtin_bit_cast(unsigned short, h);
}
__device__ __forceinline__ float bf16_f32(unsigned short h) {
  return (float)__builtin_bit_cast(__bf16, h);
}

// ---------------------------------------------------------------------------
// Fused cooperative kernel: P (weight prep) -> grid.sync -> U (node GEMM)
// -> grid.sync -> E (edge gather+MLP). One launch instead of three:
// removes 2 launch gaps, stages W2T LDS once per block (not per tile), and
// makes total GPU time visible as a single dispatch. __threadfence() before
// each grid.sync = agent-scope release (L2 writeback) so WcatT/UV written on
// one XCD are visible to readers on другом XCD after the sync.
// ---------------------------------------------------------------------------
__global__ __launch_bounds__(256, 4) void fused_kernel(
    const float* __restrict__ z, const int* ei,
    const float* __restrict__ W1, const float* __restrict__ b1,
    const float* __restrict__ W2, const float* __restrict__ b2,
    const float* __restrict__ W3, const float* __restrict__ b3,
    unsigned short* UV, unsigned short* WcatT, unsigned short* W2T,
    int* idx64_flag, float* __restrict__ out)
{
  __shared__ unsigned short lds[64 * WPITCH];  // 17408 B (E); U uses first 8704 B
  cg::grid_group grid = cg::this_grid();
  const int t = threadIdx.x, wave = t >> 6, lane = t & 63, c = lane & 15, q = lane >> 4;
  const int bid = blockIdx.x;
  const int nblk = gridDim.x;

  // ---------------- phase P: WcatT / W2T / idx64 flag ----------------
  for (int i = bid * 256 + t; i < 256 * 128 + 64 * 128; i += nblk * 256) {
    if (i < 256 * 128) {
      int jp = i >> 7, k = i & 127;
      float v = (jp < 128) ? W1[k * 128 + jp] : W1[(128 + k) * 128 + (jp - 128)];
      WcatT[jp * 128 + k] = f32_bf16(v);
    } else {
      int i2 = i - 256 * 128;
      int n = i2 >> 7, k = i2 & 127;
      W2T[n * 128 + k] = f32_bf16(W2[k * 64 + n]);
    }
  }
  if (bid == 0 && t < 64) {
    // int64 detection: odd words of the first 32 int64 entries are all 0
    int v = ei[t];
    unsigned long long odd_nz = __ballot((t & 1) && v != 0);
    if (t == 0) *idx64_flag = (odd_nz == 0ull) ? 1 : 0;
  }
  __threadfence();
  grid.sync();

  // ---------------- phase U: UV[n] = [z@W1top+b1 | z@W1bot] (bf16) ----------
  {
    unsigned short* my = &lds[wave * 16 * EPITCH];  // wave-private 2176 B
    const int gw0 = bid * 4 + wave, gstride = nblk * 4;
    for (int gw = gw0; gw < NUNIT; gw += gstride) {
      const int mbase = gw * 16;
      const int rA = mbase + c;
      const int rAc = (rA < NNODE) ? rA : 0;

      bf16x8 a0[4];
      {
        const float* zA = z + (size_t)rAc * 128 + q * 8;
        float4 fA[4][2];
#pragma unroll
        for (int kt = 0; kt < 4; ++kt) {
          fA[kt][0] = ((const float4*)(zA + kt * 32))[0];
          fA[kt][1] = ((const float4*)(zA + kt * 32))[1];
        }
#pragma unroll
        for (int kt = 0; kt < 4; ++kt) {
          const float* pa = (const float*)&fA[kt][0];
          bf16x8 oa;
#pragma unroll
          for (int j = 0; j < 8; ++j) oa[j] = (__bf16)pa[j];
          a0[kt] = oa;
        }
      }

      for (int nc = 0; nc < 4; ++nc) {
        f32x4 acc[4];
#pragma unroll
        for (int nt = 0; nt < 4; ++nt) {
          f32x4 zz = {0.f, 0.f, 0.f, 0.f};
          acc[nt] = zz;
        }
#pragma unroll
        for (int kt = 0; kt < 4; ++kt) {
#pragma unroll
          for (int nt = 0; nt < 4; ++nt) {
            bf16x8 bb = *(const bf16x8*)(WcatT + (size_t)(nc * 64 + nt * 16 + c) * 128 + kt * 32 + q * 8);
            acc[nt] = __builtin_amdgcn_mfma_f32_16x16x32_bf16(a0[kt], bb, acc[nt], 0, 0, 0);
          }
        }
        float badd[4];
#pragma unroll
        for (int nt = 0; nt < 4; ++nt) {
          int col = nc * 64 + nt * 16 + c;
          badd[nt] = (col < 128) ? b1[col] : 0.f;
        }
#pragma unroll
        for (int nt = 0; nt < 4; ++nt)
#pragma unroll
          for (int reg = 0; reg < 4; ++reg)
            my[(q * 4 + reg) * EPITCH + nt * 16 + c] = f32_bf16(acc[nt][reg] + badd[nt]);
        __asm__ volatile("s_waitcnt lgkmcnt(0)" ::: "memory");  // wave-private ds_write->ds_read

        {
          int lrow = lane >> 2, qt = lane & 3;
          int grow = mbase + lrow;
          u16x8 d0 = *(u16x8*)&my[lrow * EPITCH + qt * 16 + 0];
          u16x8 d1 = *(u16x8*)&my[lrow * EPITCH + qt * 16 + 8];
          if (grow < NNODE) {
            u16x8* dst = (u16x8*)(UV + (size_t)grow * 256 + nc * 64 + qt * 16);
            dst[0] = d0;
            dst[1] = d1;
          }
        }
        __asm__ volatile("s_waitcnt lgkmcnt(0)" ::: "memory");  // reads drain before overwrite
      }
    }
  }
  __threadfence();
  grid.sync();

  // ---------------- phase E: per-edge gather + 2-layer MLP + score ----------
  {  // stage W2T once per block (16 KB shared by all waves, all tiles)
    int n = t >> 2, qd = t & 3;
    const u16x8* src = (const u16x8*)(W2T + n * 128 + qd * 32);
    u16x8* dst = (u16x8*)(&lds[n * WPITCH + qd * 32]);
#pragma unroll
    for (int i = 0; i < 4; ++i) dst[i] = src[i];
  }
  __syncthreads();
  const int i64 = *idx64_flag;

  for (int tile = bid; tile < NTILE; tile += nblk) {
    const int ebase = tile * 128 + wave * 32;
    const int eA = ebase + c, eB = ebase + 16 + c;
    const int eAc = (eA < NEDGE) ? eA : 0;
    const int eBc = (eB < NEDGE) ? eB : 0;
    int sA, dA, sB, dB;
    if (i64) {
      const long long* e64 = (const long long*)ei;
      sA = (int)e64[eAc]; dA = (int)e64[NEDGE + eAc];
      sB = (int)e64[eBc]; dB = (int)e64[NEDGE + eBc];
    } else {
      sA = ei[eAc]; dA = ei[NEDGE + eAc];
      sB = ei[eBc]; dB = ei[NEDGE + eBc];
    }

    const u16x8* pAu = (const u16x8*)(UV + (size_t)sA * 256) + q;
    const u16x8* pAv = (const u16x8*)(UV + (size_t)dA * 256 + 128) + q;
    const u16x8* pBu = (const u16x8*)(UV + (size_t)sB * 256) + q;
    const u16x8* pBv = (const u16x8*)(UV + (size_t)dB * 256 + 128) + q;
    u16x8 rAu[4], rAv[4], rBu[4], rBv[4];
#pragma unroll
    for (int kt = 0; kt < 4; ++kt) {
      rAu[kt] = pAu[kt * 4];
      rAv[kt] = pAv[kt * 4];
      rBu[kt] = pBu[kt * 4];
      rBv[kt] = pBv[kt * 4];
    }

    f32x4 acc[2][4];
#pragma unroll
    for (int mt = 0; mt < 2; ++mt)
#pragma unroll
      for (int nt = 0; nt < 4; ++nt) {
        f32x4 zz = {0.f, 0.f, 0.f, 0.f};
        acc[mt][nt] = zz;
      }

#pragma unroll
    for (int kt = 0; kt < 4; ++kt) {
      bf16x8 a0, a1;
#pragma unroll
      for (int j = 0; j < 8; ++j) {
        a0[j] = (__bf16)fmaxf(bf16_f32(rAu[kt][j]) + bf16_f32(rAv[kt][j]), 0.f);
        a1[j] = (__bf16)fmaxf(bf16_f32(rBu[kt][j]) + bf16_f32(rBv[kt][j]), 0.f);
      }
#pragma unroll
      for (int nt = 0; nt < 4; ++nt) {
        bf16x8 bb = *(const bf16x8*)(&lds[(nt * 16 + c) * WPITCH + kt * 32 + q * 8]);
        acc[0][nt] = __builtin_amdgcn_mfma_f32_16x16x32_bf16(a0, bb, acc[0][nt], 0, 0, 0);
        acc[1][nt] = __builtin_amdgcn_mfma_f32_16x16x32_bf16(a1, bb, acc[1][nt], 0, 0, 0);
      }
    }

    float b2v[4], w3v[4];
#pragma unroll
    for (int nt = 0; nt < 4; ++nt) {
      int n = nt * 16 + c;
      b2v[nt] = b2[n];
      w3v[nt] = W3[n];
    }
    float bias3 = b3[0];

#pragma unroll
    for (int mt = 0; mt < 2; ++mt) {
      float p0 = 0.f, p1 = 0.f, p2 = 0.f, p3 = 0.f;
#pragma unroll
      for (int nt = 0; nt < 4; ++nt) {
        p0 += fmaxf(acc[mt][nt][0] + b2v[nt], 0.f) * w3v[nt];
        p1 += fmaxf(acc[mt][nt][1] + b2v[nt], 0.f) * w3v[nt];
        p2 += fmaxf(acc[mt][nt][2] + b2v[nt], 0.f) * w3v[nt];
        p3 += fmaxf(acc[mt][nt][3] + b2v[nt], 0.f) * w3v[nt];
      }
#pragma unroll
      for (int m = 1; m < 16; m <<= 1) {
        p0 += __shfl_xor(p0, m, 64);
        p1 += __shfl_xor(p1, m, 64);
        p2 += __shfl_xor(p2, m, 64);
        p3 += __shfl_xor(p3, m, 64);
      }
      if (c == 0) {
        int eb = ebase + mt * 16 + q * 4;
        if (eb + 0 < NEDGE) out[eb + 0] = p0 + bias3;
        if (eb + 1 < NEDGE) out[eb + 1] = p1 + bias3;
        if (eb + 2 < NEDGE) out[eb + 2] = p2 + bias3;
        if (eb + 3 < NEDGE) out[eb + 3] = p3 + bias3;
      }
    }
  }
}

extern "C" void kernel_launch(void* const* d_in, const int* in_sizes, int n_in,
                              void* d_out, int out_size, void* d_ws, size_t ws_size,
                              hipStream_t stream) {
  const float* z  = (const float*)d_in[0];
  const int*   ei = (const int*)d_in[1];
  const float* W1 = (const float*)d_in[2];
  const float* b1 = (const float*)d_in[3];
  const float* W2 = (const float*)d_in[4];
  const float* b2 = (const float*)d_in[5];
  const float* W3 = (const float*)d_in[6];
  const float* b3 = (const float*)d_in[7];
  float* out = (float*)d_out;

  unsigned short* UV    = (unsigned short*)d_ws;       // 50000*256 bf16 = 25.6 MB
  unsigned short* WcatT = UV + (size_t)NNODE * 256;    // 256*128 bf16
  unsigned short* W2T   = WcatT + 256 * 128;           // 64*128 bf16
  int* idx64_flag       = (int*)(W2T + 64 * 128);

  // Co-residency-safe cooperative grid (queried once; host-only calls, no
  // stream ops -> graph-capture-safe). Fallback 768 = 3 blocks/CU worst case.
  static int coopGrid = 0;
  if (coopGrid == 0) {
    int perCU = 0;
    if (hipOccupancyMaxActiveBlocksPerMultiprocessor(&perCU, fused_kernel, 256, 0) != hipSuccess ||
        perCU <= 0)
      perCU = 3;
    int nCU = 256;
    hipDeviceProp_t prop;
    int dev = 0;
    if (hipGetDevice(&dev) == hipSuccess && hipGetDeviceProperties(&prop, dev) == hipSuccess)
      nCU = prop.multiProcessorCount;
    coopGrid = perCU * nCU;
    if (coopGrid > 2048) coopGrid = 2048;
    if (coopGrid < 256) coopGrid = 256;
  }

  void* args[] = {(void*)&z,  (void*)&ei, (void*)&W1, (void*)&b1, (void*)&W2,
                  (void*)&b2, (void*)&W3, (void*)&b3, (void*)&UV, (void*)&WcatT,
                  (void*)&W2T, (void*)&idx64_flag, (void*)&out};
  hipLaunchCooperativeKernel((const void*)fused_kernel, dim3(coopGrid), dim3(256), args, 0,
                             stream);
}

// Round 5
// 159.994 us; speedup vs baseline: 2.9060x; 2.9060x over previous
//
#include <hip/hip_runtime.h>

#define NEDGE 625000
#define NNODE 50000
#define WPITCH 136  // lW pitch in shorts: 272 B rows -> 2-way bank aliasing on b128 (free)
#define EPITCH 68   // uv epilogue pitch in shorts

typedef __bf16 bf16x8 __attribute__((ext_vector_type(8)));
typedef unsigned short u16x8 __attribute__((ext_vector_type(8)));
typedef float f32x4 __attribute__((ext_vector_type(4)));

// Native casts: __bf16 cast is RNE in HW; compiler pairs them (v_cvt_pk_bf16_f32).
__device__ __forceinline__ unsigned short f32_bf16(float f) {
  __bf16 h = (__bf16)f;
  return __builtin_bit_cast(unsigned short, h);
}
__device__ __forceinline__ float bf16_f32(unsigned short h) {
  return (float)__builtin_bit_cast(__bf16, h);
}

// ---------------------------------------------------------------------------
// prep: WcatT[j'][k] = W1[k][j'] (j'<128) | W1[128+k][j'-128], bf16
//       W2T[n][k]    = W2[k][n], bf16
//       idx64_flag   = 1 if edge_index buffer looks like int64 (odd words 0)
// ---------------------------------------------------------------------------
__global__ __launch_bounds__(256) void prep_kernel(
    const float* __restrict__ W1, const float* __restrict__ W2,
    const int* __restrict__ ei,
    unsigned short* __restrict__ WcatT, unsigned short* __restrict__ W2T,
    int* __restrict__ idx64_flag)
{
  int i = blockIdx.x * 256 + threadIdx.x;
  if (i < 256 * 128) {
    int jp = i >> 7, k = i & 127;
    float v = (jp < 128) ? W1[k * 128 + jp] : W1[(128 + k) * 128 + (jp - 128)];
    WcatT[jp * 128 + k] = f32_bf16(v);
  } else if (i < 256 * 128 + 64 * 128) {
    int i2 = i - 256 * 128;
    int n = i2 >> 7, k = i2 & 127;
    W2T[n * 128 + k] = f32_bf16(W2[k * 64 + n]);
  }
  if (i == 0) {
    int allz = 1;
    for (int j = 1; j < 64; j += 2) allz &= (ei[j] == 0);
    *idx64_flag = allz;
  }
}

// ---------------------------------------------------------------------------
// uv: UV[n][0:128] = z[n]@W1_top + b1, UV[n][128:256] = z[n]@W1_bot  (bf16)
// v4: 64-thread blocks (3125 blocks = 12 waves/CU, single dispatch
// generation) + BATCHED B-fragment loads: all 16 WcatT b128 loads of an
// nc-chunk issue into bb[4][4] (64 VGPRs) behind a sched_barrier before the
// 16 MFMAs consume them. r3's loop interleaved load->mfma 1:1 = 16 serial
// ~200cy L2 round-trips per chunk with only ~3 waves/SIMD of TLP — a
// latency chain, not a bandwidth limit. WcatT is L1/L2-hot, so depth here
// is cheap (unlike edge's L3-floor gathers, round 2). VGPR ~116 < 128 cap.
// ---------------------------------------------------------------------------
__global__ __launch_bounds__(64, 4) void uv_kernel(
    const float* __restrict__ z, const float* __restrict__ b1,
    const unsigned short* __restrict__ WcatT,
    unsigned short* __restrict__ UV)
{
  __shared__ unsigned short st[16 * EPITCH];
  const int lane = threadIdx.x & 63, c = lane & 15, q = lane >> 4;
  const int mbase = blockIdx.x * 16;
  const int rA = mbase + c;
  const int rAc = (rA < NNODE) ? rA : 0;

  // A-fragments: 8 fp32 each at z[row][kt*32+q*8], convert to bf16 in regs
  bf16x8 a0[4];
  {
    const float* zA = z + (size_t)rAc * 128 + q * 8;
    float4 fA[4][2];
#pragma unroll
    for (int kt = 0; kt < 4; ++kt) {
      fA[kt][0] = ((const float4*)(zA + kt * 32))[0];
      fA[kt][1] = ((const float4*)(zA + kt * 32))[1];
    }
    __builtin_amdgcn_sched_barrier(0);  // all 8 z loads in flight
#pragma unroll
    for (int kt = 0; kt < 4; ++kt) {
      const float* pa = (const float*)&fA[kt][0];
      bf16x8 oa;
#pragma unroll
      for (int j = 0; j < 8; ++j) oa[j] = (__bf16)pa[j];
      a0[kt] = oa;
    }
  }

  for (int nc = 0; nc < 4; ++nc) {
    // batched B-frags: 16 independent b128 loads, THEN 16 MFMAs
    bf16x8 bb[4][4];
#pragma unroll
    for (int kt = 0; kt < 4; ++kt)
#pragma unroll
      for (int nt = 0; nt < 4; ++nt)
        bb[kt][nt] = *(const bf16x8*)(WcatT + (size_t)(nc * 64 + nt * 16 + c) * 128 + kt * 32 + q * 8);
    __builtin_amdgcn_sched_barrier(0);  // all 16 B loads in flight before use

    f32x4 acc[4];
#pragma unroll
    for (int nt = 0; nt < 4; ++nt) {
      f32x4 zz = {0.f, 0.f, 0.f, 0.f};
      acc[nt] = zz;
    }
#pragma unroll
    for (int kt = 0; kt < 4; ++kt)
#pragma unroll
      for (int nt = 0; nt < 4; ++nt)
        acc[nt] = __builtin_amdgcn_mfma_f32_16x16x32_bf16(a0[kt], bb[kt][nt], acc[nt], 0, 0, 0);

    float badd[4];
#pragma unroll
    for (int nt = 0; nt < 4; ++nt) {
      int col = nc * 64 + nt * 16 + c;
      badd[nt] = (col < 128) ? b1[col] : 0.f;
    }

    // stage C-chunk (16 rows x 64 cols = 1024 shorts) in wave-private LDS
#pragma unroll
    for (int nt = 0; nt < 4; ++nt)
#pragma unroll
      for (int reg = 0; reg < 4; ++reg)
        st[(q * 4 + reg) * EPITCH + nt * 16 + c] = f32_bf16(acc[nt][reg] + badd[nt]);
    __asm__ volatile("s_waitcnt lgkmcnt(0)" ::: "memory");  // wave-private: ds_write->ds_read

    // vectorized store: each lane takes 16 shorts (32 B): row lrow, cols [qt*16, qt*16+16)
    {
      int lrow = lane >> 2, qt = lane & 3;
      int grow = mbase + lrow;
      u16x8 d0 = *(u16x8*)&st[lrow * EPITCH + qt * 16 + 0];
      u16x8 d1 = *(u16x8*)&st[lrow * EPITCH + qt * 16 + 8];
      if (grow < NNODE) {
        u16x8* dst = (u16x8*)(UV + (size_t)grow * 256 + nc * 64 + qt * 16);
        dst[0] = d0;
        dst[1] = d1;
      }
    }
    __asm__ volatile("s_waitcnt lgkmcnt(0)" ::: "memory");  // reads drain before next chunk overwrites
  }
}

// ---------------------------------------------------------------------------
// edge: gather MFMA A-frags DIRECTLY from UV (no h1 LDS, no gather barrier):
// lane (c,q) reads 16B granules of rows src/dst; add+relu in regs -> frags.
// h2 = relu(h1@W2+b2) via MFMA (W2T staged once in LDS); score fp32 epilogue.
// PROVEN config (51.4-52.0 us, 3x reproduced): native casts +
// launch_bounds(256,4), NO sched fence — round-2 showed deeper pipelining is
// SLOWER here (the random 64B-granule gather stream is service-rate-bound at
// the L2-miss/L3 path; extra outstanding requests only add queueing).
// ---------------------------------------------------------------------------
__global__ __launch_bounds__(256, 4) void edge_kernel(
    const int* __restrict__ ei,
    const unsigned short* __restrict__ UV,
    const unsigned short* __restrict__ W2T,
    const float* __restrict__ b2, const float* __restrict__ W3,
    const float* __restrict__ b3, const int* __restrict__ idx64_flag,
    float* __restrict__ out)
{
  __shared__ unsigned short lW[64 * WPITCH];
  const int t = threadIdx.x, wave = t >> 6, lane = t & 63, c = lane & 15, q = lane >> 4;

  {  // stage W2T once (16 KB shared by all waves)
    int n = t >> 2, qd = t & 3;
    const u16x8* src = (const u16x8*)(W2T + n * 128 + qd * 32);
    u16x8* dst = (u16x8*)(&lW[n * WPITCH + qd * 32]);
#pragma unroll
    for (int i = 0; i < 4; ++i) dst[i] = src[i];
  }
  __syncthreads();  // the only barrier in this kernel

  const int ebase = blockIdx.x * 128 + wave * 32;
  const int eA = ebase + c, eB = ebase + 16 + c;
  const int eAc = (eA < NEDGE) ? eA : 0;
  const int eBc = (eB < NEDGE) ? eB : 0;
  int sA, dA, sB, dB;
  if (*idx64_flag) {
    const long long* e64 = (const long long*)ei;
    sA = (int)e64[eAc]; dA = (int)e64[NEDGE + eAc];
    sB = (int)e64[eBc]; dB = (int)e64[NEDGE + eBc];
  } else {
    sA = ei[eAc]; dA = ei[NEDGE + eAc];
    sB = ei[eBc]; dB = ei[NEDGE + eBc];
  }

  // 16 independent 16B gather loads (4 per kt): U-half of src, V-half of dst
  const u16x8* pAu = (const u16x8*)(UV + (size_t)sA * 256) + q;
  const u16x8* pAv = (const u16x8*)(UV + (size_t)dA * 256 + 128) + q;
  const u16x8* pBu = (const u16x8*)(UV + (size_t)sB * 256) + q;
  const u16x8* pBv = (const u16x8*)(UV + (size_t)dB * 256 + 128) + q;
  u16x8 rAu[4], rAv[4], rBu[4], rBv[4];
#pragma unroll
  for (int kt = 0; kt < 4; ++kt) {
    rAu[kt] = pAu[kt * 4];
    rAv[kt] = pAv[kt * 4];
    rBu[kt] = pBu[kt * 4];
    rBv[kt] = pBv[kt * 4];
  }

  f32x4 acc[2][4];
#pragma unroll
  for (int mt = 0; mt < 2; ++mt)
#pragma unroll
    for (int nt = 0; nt < 4; ++nt) {
      f32x4 zz = {0.f, 0.f, 0.f, 0.f};
      acc[mt][nt] = zz;
    }

#pragma unroll
  for (int kt = 0; kt < 4; ++kt) {
    bf16x8 a0, a1;
#pragma unroll
    for (int j = 0; j < 8; ++j) {
      a0[j] = (__bf16)fmaxf(bf16_f32(rAu[kt][j]) + bf16_f32(rAv[kt][j]), 0.f);
      a1[j] = (__bf16)fmaxf(bf16_f32(rBu[kt][j]) + bf16_f32(rBv[kt][j]), 0.f);
    }
#pragma unroll
    for (int nt = 0; nt < 4; ++nt) {
      bf16x8 bb = *(const bf16x8*)(&lW[(nt * 16 + c) * WPITCH + kt * 32 + q * 8]);
      acc[0][nt] = __builtin_amdgcn_mfma_f32_16x16x32_bf16(a0, bb, acc[0][nt], 0, 0, 0);
      acc[1][nt] = __builtin_amdgcn_mfma_f32_16x16x32_bf16(a1, bb, acc[1][nt], 0, 0, 0);
    }
  }

  // layer-2 bias+relu and layer-3 dot in fp32; reduce over the 16 c-lanes
  float b2v[4], w3v[4];
#pragma unroll
  for (int nt = 0; nt < 4; ++nt) {
    int n = nt * 16 + c;
    b2v[nt] = b2[n];
    w3v[nt] = W3[n];
  }
  float bias3 = b3[0];

#pragma unroll
  for (int mt = 0; mt < 2; ++mt) {
    float p0 = 0.f, p1 = 0.f, p2 = 0.f, p3 = 0.f;
#pragma unroll
    for (int nt = 0; nt < 4; ++nt) {
      p0 += fmaxf(acc[mt][nt][0] + b2v[nt], 0.f) * w3v[nt];
      p1 += fmaxf(acc[mt][nt][1] + b2v[nt], 0.f) * w3v[nt];
      p2 += fmaxf(acc[mt][nt][2] + b2v[nt], 0.f) * w3v[nt];
      p3 += fmaxf(acc[mt][nt][3] + b2v[nt], 0.f) * w3v[nt];
    }
#pragma unroll
    for (int m = 1; m < 16; m <<= 1) {
      p0 += __shfl_xor(p0, m, 64);
      p1 += __shfl_xor(p1, m, 64);
      p2 += __shfl_xor(p2, m, 64);
      p3 += __shfl_xor(p3, m, 64);
    }
    if (c == 0) {
      int eb = ebase + mt * 16 + q * 4;
      if (eb + 0 < NEDGE) out[eb + 0] = p0 + bias3;
      if (eb + 1 < NEDGE) out[eb + 1] = p1 + bias3;
      if (eb + 2 < NEDGE) out[eb + 2] = p2 + bias3;
      if (eb + 3 < NEDGE) out[eb + 3] = p3 + bias3;
    }
  }
}

extern "C" void kernel_launch(void* const* d_in, const int* in_sizes, int n_in,
                              void* d_out, int out_size, void* d_ws, size_t ws_size,
                              hipStream_t stream) {
  const float* z  = (const float*)d_in[0];
  const int*   ei = (const int*)d_in[1];
  const float* W1 = (const float*)d_in[2];
  const float* b1 = (const float*)d_in[3];
  const float* W2 = (const float*)d_in[4];
  const float* b2 = (const float*)d_in[5];
  const float* W3 = (const float*)d_in[6];
  const float* b3 = (const float*)d_in[7];
  float* out = (float*)d_out;

  unsigned short* UV    = (unsigned short*)d_ws;       // 50000*256 bf16 = 25.6 MB
  unsigned short* WcatT = UV + (size_t)NNODE * 256;    // 256*128 bf16
  unsigned short* W2T   = WcatT + 256 * 128;           // 64*128 bf16
  int* idx64_flag       = (int*)(W2T + 64 * 128);

  prep_kernel<<<dim3(160), dim3(256), 0, stream>>>(W1, W2, ei, WcatT, W2T, idx64_flag);
  uv_kernel<<<dim3((NNODE + 15) / 16), dim3(64), 0, stream>>>(z, b1, WcatT, UV);
  edge_kernel<<<dim3((NEDGE + 127) / 128), dim3(256), 0, stream>>>(
      ei, UV, W2T, b2, W3, b3, idx64_flag, out);
}

// Round 6
// 152.330 us; speedup vs baseline: 3.0522x; 1.0503x over previous
//
#include <hip/hip_runtime.h>

#define NEDGE 625000
#define NNODE 50000
#define WPITCH 136  // lW pitch in shorts: 272 B rows -> 2-way bank aliasing on b128 (free)
#define EPITCH 68   // uv epilogue pitch in shorts
#define WCPITCH 136 // in-LDS Wcat pitch in shorts: bank stride 4 dwords -> 2-way on b128 (free)

typedef __bf16 bf16x8 __attribute__((ext_vector_type(8)));
typedef unsigned short u16x8 __attribute__((ext_vector_type(8)));
typedef float f32x4 __attribute__((ext_vector_type(4)));

// Native casts: __bf16 cast is RNE in HW; compiler pairs them (v_cvt_pk_bf16_f32).
__device__ __forceinline__ unsigned short f32_bf16(float f) {
  __bf16 h = (__bf16)f;
  return __builtin_bit_cast(unsigned short, h);
}
__device__ __forceinline__ float bf16_f32(unsigned short h) {
  return (float)__builtin_bit_cast(__bf16, h);
}

// ---------------------------------------------------------------------------
// uv: UV[n][0:128] = z[n]@W1_top + b1, UV[n][128:256] = z[n]@W1_bot  (bf16)
// v5 (self-contained, kills the prep launch): each 256-thread block
// transposes W1 -> Wcat DIRECTLY INTO LDS once (69.6 KB, padded pitch 136),
// then 4 waves x 16 rows consume B-frags via ds_read_b128 (2-way aliasing =
// free). Removes prep_kernel + its graph gap + 200 MB of L2 WcatT re-reads.
// Blocks 0-1 additionally emit W2T (bf16) and idx64_flag for edge_kernel
// (consumed across the kernel boundary, same as prep did).
// LDS 78.3 KB -> 2 blocks/CU (8 waves/CU); B-latency is now LDS, not L2.
// ---------------------------------------------------------------------------
__global__ __launch_bounds__(256, 2) void uv_kernel(
    const float* __restrict__ z, const float* __restrict__ W1,
    const float* __restrict__ b1, const float* __restrict__ W2,
    const int* __restrict__ ei,
    unsigned short* __restrict__ UV, unsigned short* __restrict__ W2T,
    int* __restrict__ idx64_flag)
{
  __shared__ unsigned short lWc[256 * WCPITCH];  // Wcat[j'][k], 69632 B
  __shared__ unsigned short st[4 * 16 * EPITCH]; // per-wave epilogue, 8704 B
  const int t = threadIdx.x, wave = t >> 6, lane = t & 63, c = lane & 15, q = lane >> 4;
  const int bid = blockIdx.x;

  // side jobs for edge_kernel (cross-kernel-boundary handoff)
  if (bid < 2) {
    for (int e = bid * 4096 + t; e < (bid + 1) * 4096; e += 256) {
      int n = e >> 7, k = e & 127;
      W2T[n * 128 + k] = f32_bf16(W2[k * 64 + n]);
    }
  }
  if (bid == 0 && t == 0) {
    int allz = 1;
    for (int j = 1; j < 64; j += 2) allz &= (ei[j] == 0);
    *idx64_flag = allz;
  }

  // in-LDS transpose: lWc[j'][k] = W1[k][j'] (j'<128) | W1[128+k][j'-128]
  // reads coalesced (2 W1 rows per iteration); one-time strided ds_writes.
  for (int e = t; e < 256 * 128; e += 256) {
    int r = e >> 7, j = e & 127;
    float v = W1[r * 128 + j];
    int jp = (r < 128) ? j : (128 + j);
    int k = r & 127;
    lWc[jp * WCPITCH + k] = f32_bf16(v);
  }
  __syncthreads();

  const int mbase = bid * 64 + wave * 16;
  const int rA = mbase + c;
  const int rAc = (rA < NNODE) ? rA : 0;

  // A-fragments: 8 fp32 each at z[row][kt*32+q*8], convert to bf16 in regs
  bf16x8 a0[4];
  {
    const float* zA = z + (size_t)rAc * 128 + q * 8;
    float4 fA[4][2];
#pragma unroll
    for (int kt = 0; kt < 4; ++kt) {
      fA[kt][0] = ((const float4*)(zA + kt * 32))[0];
      fA[kt][1] = ((const float4*)(zA + kt * 32))[1];
    }
#pragma unroll
    for (int kt = 0; kt < 4; ++kt) {
      const float* pa = (const float*)&fA[kt][0];
      bf16x8 oa;
#pragma unroll
      for (int j = 0; j < 8; ++j) oa[j] = (__bf16)pa[j];
      a0[kt] = oa;
    }
  }

  unsigned short* my = &st[wave * 16 * EPITCH];

  for (int nc = 0; nc < 4; ++nc) {
    f32x4 acc[4];
#pragma unroll
    for (int nt = 0; nt < 4; ++nt) {
      f32x4 zz = {0.f, 0.f, 0.f, 0.f};
      acc[nt] = zz;
    }
#pragma unroll
    for (int kt = 0; kt < 4; ++kt)
#pragma unroll
      for (int nt = 0; nt < 4; ++nt) {
        bf16x8 bb = *(const bf16x8*)(&lWc[(nc * 64 + nt * 16 + c) * WCPITCH + kt * 32 + q * 8]);
        acc[nt] = __builtin_amdgcn_mfma_f32_16x16x32_bf16(a0[kt], bb, acc[nt], 0, 0, 0);
      }

    float badd[4];
#pragma unroll
    for (int nt = 0; nt < 4; ++nt) {
      int col = nc * 64 + nt * 16 + c;
      badd[nt] = (col < 128) ? b1[col] : 0.f;
    }

    // stage C-chunk (16 rows x 64 cols = 1024 shorts) in wave-private LDS
#pragma unroll
    for (int nt = 0; nt < 4; ++nt)
#pragma unroll
      for (int reg = 0; reg < 4; ++reg)
        my[(q * 4 + reg) * EPITCH + nt * 16 + c] = f32_bf16(acc[nt][reg] + badd[nt]);
    __asm__ volatile("s_waitcnt lgkmcnt(0)" ::: "memory");  // wave-private: ds_write->ds_read

    // vectorized store: each lane takes 16 shorts (32 B)
    {
      int lrow = lane >> 2, qt = lane & 3;
      int grow = mbase + lrow;
      u16x8 d0 = *(u16x8*)&my[lrow * EPITCH + qt * 16 + 0];
      u16x8 d1 = *(u16x8*)&my[lrow * EPITCH + qt * 16 + 8];
      if (grow < NNODE) {
        u16x8* dst = (u16x8*)(UV + (size_t)grow * 256 + nc * 64 + qt * 16);
        dst[0] = d0;
        dst[1] = d1;
      }
    }
    __asm__ volatile("s_waitcnt lgkmcnt(0)" ::: "memory");  // reads drain before next chunk overwrites
  }
}

// ---------------------------------------------------------------------------
// edge: gather MFMA A-frags DIRECTLY from UV (no h1 LDS, no gather barrier):
// lane (c,q) reads 16B granules of rows src/dst; add+relu in regs -> frags.
// h2 = relu(h1@W2+b2) via MFMA (W2T staged once in LDS); score fp32 epilogue.
// PROVEN config (51.4-52.1 us, 4x reproduced): native casts +
// launch_bounds(256,4), NO sched fence — round-2 showed deeper pipelining is
// SLOWER here (the random 64B-granule gather stream is service-rate-bound at
// the L2-miss/L3 path; extra outstanding requests only add queueing).
// DO NOT TOUCH the memory structure of this kernel.
// ---------------------------------------------------------------------------
__global__ __launch_bounds__(256, 4) void edge_kernel(
    const int* __restrict__ ei,
    const unsigned short* __restrict__ UV,
    const unsigned short* __restrict__ W2T,
    const float* __restrict__ b2, const float* __restrict__ W3,
    const float* __restrict__ b3, const int* __restrict__ idx64_flag,
    float* __restrict__ out)
{
  __shared__ unsigned short lW[64 * WPITCH];
  const int t = threadIdx.x, wave = t >> 6, lane = t & 63, c = lane & 15, q = lane >> 4;

  {  // stage W2T once (16 KB shared by all waves)
    int n = t >> 2, qd = t & 3;
    const u16x8* src = (const u16x8*)(W2T + n * 128 + qd * 32);
    u16x8* dst = (u16x8*)(&lW[n * WPITCH + qd * 32]);
#pragma unroll
    for (int i = 0; i < 4; ++i) dst[i] = src[i];
  }
  __syncthreads();  // the only barrier in this kernel

  const int ebase = blockIdx.x * 128 + wave * 32;
  const int eA = ebase + c, eB = ebase + 16 + c;
  const int eAc = (eA < NEDGE) ? eA : 0;
  const int eBc = (eB < NEDGE) ? eB : 0;
  int sA, dA, sB, dB;
  if (*idx64_flag) {
    const long long* e64 = (const long long*)ei;
    sA = (int)e64[eAc]; dA = (int)e64[NEDGE + eAc];
    sB = (int)e64[eBc]; dB = (int)e64[NEDGE + eBc];
  } else {
    sA = ei[eAc]; dA = ei[NEDGE + eAc];
    sB = ei[eBc]; dB = ei[NEDGE + eBc];
  }

  // 16 independent 16B gather loads (4 per kt): U-half of src, V-half of dst
  const u16x8* pAu = (const u16x8*)(UV + (size_t)sA * 256) + q;
  const u16x8* pAv = (const u16x8*)(UV + (size_t)dA * 256 + 128) + q;
  const u16x8* pBu = (const u16x8*)(UV + (size_t)sB * 256) + q;
  const u16x8* pBv = (const u16x8*)(UV + (size_t)dB * 256 + 128) + q;
  u16x8 rAu[4], rAv[4], rBu[4], rBv[4];
#pragma unroll
  for (int kt = 0; kt < 4; ++kt) {
    rAu[kt] = pAu[kt * 4];
    rAv[kt] = pAv[kt * 4];
    rBu[kt] = pBu[kt * 4];
    rBv[kt] = pBv[kt * 4];
  }

  f32x4 acc[2][4];
#pragma unroll
  for (int mt = 0; mt < 2; ++mt)
#pragma unroll
    for (int nt = 0; nt < 4; ++nt) {
      f32x4 zz = {0.f, 0.f, 0.f, 0.f};
      acc[mt][nt] = zz;
    }

#pragma unroll
  for (int kt = 0; kt < 4; ++kt) {
    bf16x8 a0, a1;
#pragma unroll
    for (int j = 0; j < 8; ++j) {
      a0[j] = (__bf16)fmaxf(bf16_f32(rAu[kt][j]) + bf16_f32(rAv[kt][j]), 0.f);
      a1[j] = (__bf16)fmaxf(bf16_f32(rBu[kt][j]) + bf16_f32(rBv[kt][j]), 0.f);
    }
#pragma unroll
    for (int nt = 0; nt < 4; ++nt) {
      bf16x8 bb = *(const bf16x8*)(&lW[(nt * 16 + c) * WPITCH + kt * 32 + q * 8]);
      acc[0][nt] = __builtin_amdgcn_mfma_f32_16x16x32_bf16(a0, bb, acc[0][nt], 0, 0, 0);
      acc[1][nt] = __builtin_amdgcn_mfma_f32_16x16x32_bf16(a1, bb, acc[1][nt], 0, 0, 0);
    }
  }

  // layer-2 bias+relu and layer-3 dot in fp32; reduce over the 16 c-lanes
  float b2v[4], w3v[4];
#pragma unroll
  for (int nt = 0; nt < 4; ++nt) {
    int n = nt * 16 + c;
    b2v[nt] = b2[n];
    w3v[nt] = W3[n];
  }
  float bias3 = b3[0];

#pragma unroll
  for (int mt = 0; mt < 2; ++mt) {
    float p0 = 0.f, p1 = 0.f, p2 = 0.f, p3 = 0.f;
#pragma unroll
    for (int nt = 0; nt < 4; ++nt) {
      p0 += fmaxf(acc[mt][nt][0] + b2v[nt], 0.f) * w3v[nt];
      p1 += fmaxf(acc[mt][nt][1] + b2v[nt], 0.f) * w3v[nt];
      p2 += fmaxf(acc[mt][nt][2] + b2v[nt], 0.f) * w3v[nt];
      p3 += fmaxf(acc[mt][nt][3] + b2v[nt], 0.f) * w3v[nt];
    }
#pragma unroll
    for (int m = 1; m < 16; m <<= 1) {
      p0 += __shfl_xor(p0, m, 64);
      p1 += __shfl_xor(p1, m, 64);
      p2 += __shfl_xor(p2, m, 64);
      p3 += __shfl_xor(p3, m, 64);
    }
    if (c == 0) {
      int eb = ebase + mt * 16 + q * 4;
      if (eb + 0 < NEDGE) out[eb + 0] = p0 + bias3;
      if (eb + 1 < NEDGE) out[eb + 1] = p1 + bias3;
      if (eb + 2 < NEDGE) out[eb + 2] = p2 + bias3;
      if (eb + 3 < NEDGE) out[eb + 3] = p3 + bias3;
    }
  }
}

extern "C" void kernel_launch(void* const* d_in, const int* in_sizes, int n_in,
                              void* d_out, int out_size, void* d_ws, size_t ws_size,
                              hipStream_t stream) {
  const float* z  = (const float*)d_in[0];
  const int*   ei = (const int*)d_in[1];
  const float* W1 = (const float*)d_in[2];
  const float* b1 = (const float*)d_in[3];
  const float* W2 = (const float*)d_in[4];
  const float* b2 = (const float*)d_in[5];
  const float* W3 = (const float*)d_in[6];
  const float* b3 = (const float*)d_in[7];
  float* out = (float*)d_out;

  unsigned short* UV  = (unsigned short*)d_ws;       // 50000*256 bf16 = 25.6 MB
  unsigned short* W2T = UV + (size_t)NNODE * 256;    // 64*128 bf16
  int* idx64_flag     = (int*)(W2T + 64 * 128);

  uv_kernel<<<dim3((NNODE + 63) / 64), dim3(256), 0, stream>>>(
      z, W1, b1, W2, ei, UV, W2T, idx64_flag);
  edge_kernel<<<dim3((NEDGE + 127) / 128), dim3(256), 0, stream>>>(
      ei, UV, W2T, b2, W3, b3, idx64_flag, out);
}